// Round 12
// baseline (156.085 us; speedup 1.0000x reference)
//
#include <hip/hip_runtime.h>
#include <hip/hip_bf16.h>
#include <stdint.h>

#define MB_ 8192
#define FD  512
#define OD  512
#define KD  8704     // F*16 + F (basis + residual)
#define KBASIS 8192
// bt2 tiled geometry: chunk(ct, ks, o) ; ks in [0,1088), o in [0,128), 16B chunks
#define BT_KS   1088
#define BT_CHUNKS_PER_CT (BT_KS * 128)          // 139264
#define BT_BYTES_PER_CT  (BT_CHUNKS_PER_CT * 16) // 2228224

typedef __attribute__((ext_vector_type(4))) float f32x4;
typedef __attribute__((ext_vector_type(8))) short bf16x8;
typedef __attribute__((ext_vector_type(4))) unsigned int u32x4;
typedef __attribute__((ext_vector_type(2))) unsigned int u32x2;

__device__ __forceinline__ void gload_lds16(const void* g, void* l) {
  __builtin_amdgcn_global_load_lds((const __attribute__((address_space(1))) void*)g,
                                   (__attribute__((address_space(3))) void*)l,
                                   16, 0, 0);
}

__device__ __forceinline__ uint32_t bf_rtn(float f) {
  uint32_t u = __float_as_uint(f);
  return (u + 0x7fffu + ((u >> 16) & 1u)) >> 16;
}

// packed bf16 pair (a in low 16, b in high 16) via HW v_cvt_pk_bf16_f32
__device__ __forceinline__ uint32_t pk(float a, float b) {
  uint32_t r;
  asm("v_cvt_pk_bf16_f32 %0, %1, %2" : "=v"(r) : "v"(a), "v"(b));
  return r;
}

// ---------------- phase 1: t = tanh(x) fp32, xbf = bf16(x) ----------------
__global__ __launch_bounds__(256) void k_tanh(const float* __restrict__ x,
                                              float* __restrict__ t,
                                              uint16_t* __restrict__ xbf) {
  int i = blockIdx.x * 256 + threadIdx.x;   // 0 .. 2^20-1, 4 elems each
  f32x4 v = ((const f32x4*)x)[i];
  f32x4 tv;
  tv[0] = tanhf(v[0]); tv[1] = tanhf(v[1]);
  tv[2] = tanhf(v[2]); tv[3] = tanhf(v[3]);
  ((f32x4*)t)[i] = tv;
  u32x2 p;
  p[0] = pk(v[0], v[1]);
  p[1] = pk(v[2], v[3]);
  ((u32x2*)xbf)[i] = p;
}

// ---------------- phase 2: bt2 tiled repack, SLOT-PERMUTED ------------------
// chunk(ct, ks, o) holds bf16 of B's k-slot ks for out-col ct*128+o.
// NEW slot order within each K-step (8 slots): (f0L,f1L,f2L,f3L,f0H,f1H,f2H,f3H)
// where fp = feature step*4+p, L = terms T0..7, H = T8..15. This makes the
// A-side fragment pair for lane l4 = BOTH halves of ONE feature -> one chain,
// no cross-lane exchange. Residual slots (ks >= 1024) keep the linear map.
__global__ __launch_bounds__(256) void k_bt(const float* __restrict__ coeffs,
                                            const float* __restrict__ bw,
                                            uint16_t* __restrict__ bt2,
                                            float* __restrict__ out) {
  int tid = blockIdx.x * 256 + threadIdx.x;  // 0..262143
  {
    int o = tid & 511, i = tid >> 9;         // feature i, out-col o
    const f32x4* src = (const f32x4*)(coeffs + (((size_t)(i * 512 + o)) << 4));
    f32x4 c0 = src[0], c1 = src[1], c2 = src[2], c3 = src[3];
    u32x4 qa, qb;
    qa[0] = pk(c0[0], c0[1]);
    qa[1] = pk(c0[2], c0[3]);
    qa[2] = pk(c1[0], c1[1]);
    qa[3] = pk(c1[2], c1[3]);
    qb[0] = pk(c2[0], c2[1]);
    qb[1] = pk(c2[2], c2[3]);
    qb[2] = pk(c3[0], c3[1]);
    qb[3] = pk(c3[2], c3[3]);
    int slo = ((i >> 2) << 3) | (i & 3);     // lo-half slot of feature i
    size_t cidx = (size_t)(o >> 7) * BT_CHUNKS_PER_CT + (size_t)slo * 128 + (o & 127);
    u32x4* base = (u32x4*)bt2;
    base[cidx]       = qa;   // T0..T7
    base[cidx + 512] = qb;   // T8..T15 (slot + 4)
  }
  {
    int o2 = tid >> 9, i2 = tid & 511;
    size_t cidx = (size_t)(o2 >> 7) * BT_CHUNKS_PER_CT + (size_t)(1024 + (i2 >> 3)) * 128 + (o2 & 127);
    bt2[cidx * 8 + (i2 & 7)] = (uint16_t)bf_rtn(bw[i2 * 512 + o2]);
  }
  if (tid == 0) out[(size_t)MB_ * OD] = 0.0f;   // kl output
}

// ---------------- phase 3: fused GEMM, register-A, 16 waves 4x4 -------------
// C[8192,512] = A[8192,8704] @ B[8704,512].  Tile 128x128, BK=64.
// ROUND-12: (1) slot-permuted B -> one chain per lane, zero exchange;
// (2) wave grid 4x4 (tile 32x32) -> B LDS re-read amplification 8x -> 4x
// (128 -> 64 ds_read_b128 per step per CU; DS pipe was the r10/r11 wall).
__global__ __launch_bounds__(1024, 4) void k_gemm(const float* __restrict__ t,
                                                  const uint16_t* __restrict__ xbf,
                                                  const uint16_t* __restrict__ bt2,
                                                  float* __restrict__ out) {
  __shared__ __align__(128) char lds[36864];  // B dbuf 2x16KB | t dbuf 2x2KB

  const int tid  = threadIdx.x;       // 0..1023
  const int lane = tid & 63;
  const int wid  = tid >> 6;          // 0..15
  const int wr   = wid >> 2;          // 0..3 (row group of 32)
  const int wc   = wid & 3;           // 0..3 (col group of 32)
  const int l15  = lane & 15, l4 = lane >> 4;   // l4 = this lane's feature slot

  // bijective XCD swizzle: each XCD gets 8 row-tiles x 4 col-tiles
  int bx  = blockIdx.x;               // 0..255
  int idx = bx >> 3;
  int rt  = (bx & 7) * 8 + (idx >> 2);   // 0..63
  int ct  = idx & 3;                     // 0..3
  const int brow = rt << 7, bcol = ct << 7;

  const char* btbase = (const char*)bt2 + (size_t)ct * BT_BYTES_PER_CT;
  const int row = brow + wr * 32 + l15;              // m=0 row of this lane
  const uint16_t* x0 = xbf + (size_t)row * FD;
  const uint16_t* x1 = x0 + (size_t)16 * FD;         // m=1 row

  // hoisted LDS base pointers (buf offset compile-time +16384/+2048)
  const char* bb0 = lds + l4 * 2048 + (wc * 32 + l15) * 16;       // B reads
  const char* tb0 = lds + 32768 + (wr * 32 + l15) * 16 + l4 * 4;  // t reads
  char* sBl = lds + tid * 16;                                     // B stage dst
  char* sTl = lds + 32768 + wid * 1024 + lane * 16;               // t stage dst

  // running global staging pointers
  const char* sBg = btbase + (size_t)tid * 16;                    // +16384/step
  const char* sTg = (const char*)t + (((size_t)(brow + wid * 64 + lane)) * FD) * 4; // +16/step

  f32x4 acc[2][2];
#pragma unroll
  for (int m = 0; m < 2; ++m)
#pragma unroll
    for (int n = 0; n < 2; ++n) acc[m][n] = (f32x4)0.0f;

  u32x4 pf00 = {}, pf01 = {}, pf10 = {}, pf11 = {};   // residual prefetch

  // prologue: stage B and t for step 0 into buf 0
  gload_lds16(sBg, sBl);
  sBg += 16384;
  if (wid < 2) gload_lds16(sTg, sTl);
  sTg += 16;

  auto body = [&](int step, int buf) {
    // snapshot THIS step's residual data BEFORE the next prefetch overwrites
    u32x4 af00 = pf00, af01 = pf01, af10 = pf10, af11 = pf11;  // af[m][h]

    __syncthreads();                  // buf fully staged (B + t)

    if (step < 135) {
      gload_lds16(sBg, sBl + (buf ^ 1) * 16384);
      sBg += 16384;
      if (step + 1 < 128) {
        if (wid < 2) gload_lds16(sTg, sTl + (buf ^ 1) * 2048);
        sTg += 16;
      } else {                        // prefetch xbf frags for next residual step
        int kres = ((step + 1 - 128) << 6) + l4 * 8;
        pf00 = *(const u32x4*)(x0 + kres);
        pf01 = *(const u32x4*)(x0 + kres + 32);
        pf10 = *(const u32x4*)(x1 + kres);
        pf11 = *(const u32x4*)(x1 + kres + 32);
      }
    }

    if (step < 128) {                 // basis: ONE chain per (lane,row)
      const char* tb = tb0 + buf * 2048;
#pragma unroll
      for (int m = 0; m < 2; ++m) {
        float tv = *(const float*)(tb + m * 256);   // feature step*4 + l4, row m
        float c2 = tv + tv;
        float T0 = 1.0f, T1 = tv;
        float T2  = __builtin_fmaf(c2, T1,  -T0);
        float T3  = __builtin_fmaf(c2, T2,  -T1);
        float T4  = __builtin_fmaf(c2, T3,  -T2);
        float T5  = __builtin_fmaf(c2, T4,  -T3);
        float T6  = __builtin_fmaf(c2, T5,  -T4);
        float T7  = __builtin_fmaf(c2, T6,  -T5);
        float T8  = __builtin_fmaf(c2, T7,  -T6);
        float T9  = __builtin_fmaf(c2, T8,  -T7);
        float T10 = __builtin_fmaf(c2, T9,  -T8);
        float T11 = __builtin_fmaf(c2, T10, -T9);
        float T12 = __builtin_fmaf(c2, T11, -T10);
        float T13 = __builtin_fmaf(c2, T12, -T11);
        float T14 = __builtin_fmaf(c2, T13, -T12);
        float T15 = __builtin_fmaf(c2, T14, -T13);
        u32x4 lo, hi;
        lo[0] = pk(T0,  T1);  lo[1] = pk(T2,  T3);
        lo[2] = pk(T4,  T5);  lo[3] = pk(T6,  T7);
        hi[0] = pk(T8,  T9);  hi[1] = pk(T10, T11);
        hi[2] = pk(T12, T13); hi[3] = pk(T14, T15);
        if (m == 0) { af00 = lo; af01 = hi; }
        else        { af10 = lo; af11 = hi; }
      }
    }

    const char* bb = bb0 + buf * 16384;
    bf16x8 b00 = *(const bf16x8*)(bb);                 // h=0, n=0
    bf16x8 b01 = *(const bf16x8*)(bb + 256);           // h=0, n=1
    bf16x8 b10 = *(const bf16x8*)(bb + 8192);          // h=1, n=0
    bf16x8 b11 = *(const bf16x8*)(bb + 8192 + 256);    // h=1, n=1
    bf16x8 a00 = *(const bf16x8*)&af00;   // m=0 h=0
    bf16x8 a01 = *(const bf16x8*)&af01;   // m=0 h=1
    bf16x8 a10 = *(const bf16x8*)&af10;   // m=1 h=0
    bf16x8 a11 = *(const bf16x8*)&af11;   // m=1 h=1
    acc[0][0] = __builtin_amdgcn_mfma_f32_16x16x32_bf16(a00, b00, acc[0][0], 0, 0, 0);
    acc[0][1] = __builtin_amdgcn_mfma_f32_16x16x32_bf16(a00, b01, acc[0][1], 0, 0, 0);
    acc[1][0] = __builtin_amdgcn_mfma_f32_16x16x32_bf16(a10, b00, acc[1][0], 0, 0, 0);
    acc[1][1] = __builtin_amdgcn_mfma_f32_16x16x32_bf16(a10, b01, acc[1][1], 0, 0, 0);
    acc[0][0] = __builtin_amdgcn_mfma_f32_16x16x32_bf16(a01, b10, acc[0][0], 0, 0, 0);
    acc[0][1] = __builtin_amdgcn_mfma_f32_16x16x32_bf16(a01, b11, acc[0][1], 0, 0, 0);
    acc[1][0] = __builtin_amdgcn_mfma_f32_16x16x32_bf16(a11, b10, acc[1][0], 0, 0, 0);
    acc[1][1] = __builtin_amdgcn_mfma_f32_16x16x32_bf16(a11, b11, acc[1][1], 0, 0, 0);
  };

  for (int s = 0; s < 136; s += 2) {  // 2-step unroll: buf compile-time
    body(s, 0);
    body(s + 1, 1);
  }

  // epilogue: C/D layout col=l&15, row=(l>>4)*4+r  [m89]
#pragma unroll
  for (int m = 0; m < 2; ++m)
#pragma unroll
    for (int n = 0; n < 2; ++n)
#pragma unroll
      for (int r = 0; r < 4; ++r) {
        int grow = brow + wr * 32 + m * 16 + l4 * 4 + r;
        int gcol = bcol + wc * 32 + n * 16 + l15;
        out[(size_t)grow * OD + gcol] = acc[m][n][r];
      }
}

extern "C" void kernel_launch(void* const* d_in, const int* in_sizes, int n_in,
                              void* d_out, int out_size, void* d_ws, size_t ws_size,
                              hipStream_t stream) {
  const float* x      = (const float*)d_in[0];
  const float* coeffs = (const float*)d_in[1];
  const float* bw     = (const float*)d_in[2];
  float* out = (float*)d_out;
  char* ws = (char*)d_ws;

  float*    t   = (float*)ws;                                  // 16 MB fp32 tanh
  uint16_t* xbf = (uint16_t*)(ws + (size_t)16777216);          // 8 MB bf16 x
  uint16_t* bt2 = (uint16_t*)(ws + (size_t)16777216 + 8388608);// 8.5 MB tiled B

  k_tanh<<<4096, 256, 0, stream>>>(x, t, xbf);
  k_bt<<<1024, 256, 0, stream>>>(coeffs, bw, bt2, out);
  k_gemm<<<256, 1024, 0, stream>>>(t, xbf, bt2, out);
}

// Round 13
// 143.170 us; speedup vs baseline: 1.0902x; 1.0902x over previous
//
#include <hip/hip_runtime.h>
#include <hip/hip_bf16.h>
#include <stdint.h>

#define MB_ 8192
#define FD  512
#define OD  512
#define KD  8704     // F*16 + F (basis + residual)
#define KBASIS 8192
// bt2 tiled geometry: chunk(ct, ks, o) ; ks in [0,1088), o in [0,128), 16B chunks
#define BT_KS   1088
#define BT_CHUNKS_PER_CT (BT_KS * 128)          // 139264
#define BT_BYTES_PER_CT  (BT_CHUNKS_PER_CT * 16) // 2228224

typedef __attribute__((ext_vector_type(4))) float f32x4;
typedef __attribute__((ext_vector_type(8))) short bf16x8;
typedef __attribute__((ext_vector_type(4))) unsigned int u32x4;
typedef __attribute__((ext_vector_type(2))) unsigned int u32x2;

__device__ __forceinline__ void gload_lds16(const void* g, void* l) {
  __builtin_amdgcn_global_load_lds((const __attribute__((address_space(1))) void*)g,
                                   (__attribute__((address_space(3))) void*)l,
                                   16, 0, 0);
}

__device__ __forceinline__ uint32_t bf_rtn(float f) {
  uint32_t u = __float_as_uint(f);
  return (u + 0x7fffu + ((u >> 16) & 1u)) >> 16;
}

// packed bf16 pair (a in low 16, b in high 16) via HW v_cvt_pk_bf16_f32
__device__ __forceinline__ uint32_t pk(float a, float b) {
  uint32_t r;
  asm("v_cvt_pk_bf16_f32 %0, %1, %2" : "=v"(r) : "v"(a), "v"(b));
  return r;
}

// ---------------- phase 1: t = tanh(x) fp32, xbf = bf16(x) ----------------
__global__ __launch_bounds__(256) void k_tanh(const float* __restrict__ x,
                                              float* __restrict__ t,
                                              uint16_t* __restrict__ xbf) {
  int i = blockIdx.x * 256 + threadIdx.x;   // 0 .. 2^20-1, 4 elems each
  f32x4 v = ((const f32x4*)x)[i];
  f32x4 tv;
  tv[0] = tanhf(v[0]); tv[1] = tanhf(v[1]);
  tv[2] = tanhf(v[2]); tv[3] = tanhf(v[3]);
  ((f32x4*)t)[i] = tv;
  u32x2 p;
  p[0] = pk(v[0], v[1]);
  p[1] = pk(v[2], v[3]);
  ((u32x2*)xbf)[i] = p;
}

// ---------------- phase 2: bt2 tiled repack, SLOT-PERMUTED (PROVEN r12) -----
// chunk(ct, ks, o): k-slot order per K-step = (f0L,f1L,f2L,f3L,f0H,f1H,f2H,f3H)
// -> A-fragment pair for lane l4 = both halves of ONE feature (one chain/lane).
__global__ __launch_bounds__(256) void k_bt(const float* __restrict__ coeffs,
                                            const float* __restrict__ bw,
                                            uint16_t* __restrict__ bt2,
                                            float* __restrict__ out) {
  int tid = blockIdx.x * 256 + threadIdx.x;  // 0..262143
  {
    int o = tid & 511, i = tid >> 9;         // feature i, out-col o
    const f32x4* src = (const f32x4*)(coeffs + (((size_t)(i * 512 + o)) << 4));
    f32x4 c0 = src[0], c1 = src[1], c2 = src[2], c3 = src[3];
    u32x4 qa, qb;
    qa[0] = pk(c0[0], c0[1]);
    qa[1] = pk(c0[2], c0[3]);
    qa[2] = pk(c1[0], c1[1]);
    qa[3] = pk(c1[2], c1[3]);
    qb[0] = pk(c2[0], c2[1]);
    qb[1] = pk(c2[2], c2[3]);
    qb[2] = pk(c3[0], c3[1]);
    qb[3] = pk(c3[2], c3[3]);
    int slo = ((i >> 2) << 3) | (i & 3);     // lo-half slot of feature i
    size_t cidx = (size_t)(o >> 7) * BT_CHUNKS_PER_CT + (size_t)slo * 128 + (o & 127);
    u32x4* base = (u32x4*)bt2;
    base[cidx]       = qa;   // T0..T7
    base[cidx + 512] = qb;   // T8..T15 (slot + 4)
  }
  {
    int o2 = tid >> 9, i2 = tid & 511;
    size_t cidx = (size_t)(o2 >> 7) * BT_CHUNKS_PER_CT + (size_t)(1024 + (i2 >> 3)) * 128 + (o2 & 127);
    bt2[cidx * 8 + (i2 & 7)] = (uint16_t)bf_rtn(bw[i2 * 512 + o2]);
  }
  if (tid == 0) out[(size_t)MB_ * OD] = 0.0f;   // kl output
}

// ---------------- phase 3: fused GEMM, register-A, 2 blocks/CU --------------
// C[8192,512] = A[8192,8704] @ B[8704,512].  Tile 64x128, BK=64.
// ROUND-13: grid 512 x 512 threads (8 waves, 2x4, wave tile 32x32) -> TWO
// blocks co-resident per CU; one block's compute fills the other's barrier
// vmcnt-drain (r9-r12 were 1 block/CU: all waves parked at every barrier).
// Per-lane work identical to r12 (one chain, 8 MFMA, acc[2][2]).
__global__ __launch_bounds__(512, 4) void k_gemm(const float* __restrict__ t,
                                                 const uint16_t* __restrict__ xbf,
                                                 const uint16_t* __restrict__ bt2,
                                                 float* __restrict__ out) {
  __shared__ __align__(128) char lds[34816];  // B dbuf 2x16KB | t dbuf 2x1KB

  const int tid  = threadIdx.x;       // 0..511
  const int lane = tid & 63;
  const int wid  = tid >> 6;          // 0..7
  const int wr   = wid >> 2;          // 0..1 (row group of 32)
  const int wc   = wid & 3;           // 0..3 (col group of 32)
  const int l15  = lane & 15, l4 = lane >> 4;   // l4 = this lane's feature slot

  // bijective XCD swizzle: 512 blocks, each XCD a contiguous 16-rt band x 4 ct
  int bx  = blockIdx.x;               // 0..511
  int idx = bx >> 3;                  // 0..63
  int rt  = (bx & 7) * 16 + (idx >> 2);  // 0..127
  int ct  = idx & 3;                     // 0..3
  const int brow = rt << 6, bcol = ct << 7;

  const char* btbase = (const char*)bt2 + (size_t)ct * BT_BYTES_PER_CT;
  const int row = brow + wr * 32 + l15;              // m=0 row of this lane
  const uint16_t* x0 = xbf + (size_t)row * FD;
  const uint16_t* x1 = x0 + (size_t)16 * FD;         // m=1 row

  // hoisted LDS base pointers (buf offset compile-time +16384/+1024)
  const char* bb0 = lds + l4 * 2048 + (wc * 32 + l15) * 16;       // B reads
  const char* tb0 = lds + 32768 + (wr * 32 + l15) * 16 + l4 * 4;  // t reads
  char* sBl = lds + tid * 16;                                     // B stage dst
  char* sTl = lds + 32768 + lane * 16;                            // t stage dst

  // running global staging pointers
  const char* sBg = btbase + (size_t)tid * 16;                    // +16384/step
  const char* sTg = (const char*)t + (((size_t)(brow + lane)) * FD) * 4; // +16/step

  f32x4 acc[2][2];
#pragma unroll
  for (int m = 0; m < 2; ++m)
#pragma unroll
    for (int n = 0; n < 2; ++n) acc[m][n] = (f32x4)0.0f;

  u32x4 pf00 = {}, pf01 = {}, pf10 = {}, pf11 = {};   // residual prefetch

  // prologue: stage B and t for step 0 into buf 0
  gload_lds16(sBg, sBl);
  gload_lds16(sBg + 8192, sBl + 8192);
  sBg += 16384;
  if (wid == 0) gload_lds16(sTg, sTl);
  sTg += 16;

  auto body = [&](int step, int buf) {
    // snapshot THIS step's residual data BEFORE the next prefetch overwrites
    u32x4 af00 = pf00, af01 = pf01, af10 = pf10, af11 = pf11;  // af[m][h]

    __syncthreads();                  // buf fully staged (B + t)

    if (step < 135) {
      gload_lds16(sBg, sBl + (buf ^ 1) * 16384);
      gload_lds16(sBg + 8192, sBl + (buf ^ 1) * 16384 + 8192);
      sBg += 16384;
      if (step + 1 < 128) {
        if (wid == 0) gload_lds16(sTg, sTl + (buf ^ 1) * 1024);
        sTg += 16;
      } else {                        // prefetch xbf frags for next residual step
        int kres = ((step + 1 - 128) << 6) + l4 * 8;
        pf00 = *(const u32x4*)(x0 + kres);
        pf01 = *(const u32x4*)(x0 + kres + 32);
        pf10 = *(const u32x4*)(x1 + kres);
        pf11 = *(const u32x4*)(x1 + kres + 32);
      }
    }

    if (step < 128) {                 // basis: ONE chain per (lane,row)
      const char* tb = tb0 + buf * 1024;
#pragma unroll
      for (int m = 0; m < 2; ++m) {
        float tv = *(const float*)(tb + m * 256);   // feature step*4 + l4, row m
        float c2 = tv + tv;
        float T0 = 1.0f, T1 = tv;
        float T2  = __builtin_fmaf(c2, T1,  -T0);
        float T3  = __builtin_fmaf(c2, T2,  -T1);
        float T4  = __builtin_fmaf(c2, T3,  -T2);
        float T5  = __builtin_fmaf(c2, T4,  -T3);
        float T6  = __builtin_fmaf(c2, T5,  -T4);
        float T7  = __builtin_fmaf(c2, T6,  -T5);
        float T8  = __builtin_fmaf(c2, T7,  -T6);
        float T9  = __builtin_fmaf(c2, T8,  -T7);
        float T10 = __builtin_fmaf(c2, T9,  -T8);
        float T11 = __builtin_fmaf(c2, T10, -T9);
        float T12 = __builtin_fmaf(c2, T11, -T10);
        float T13 = __builtin_fmaf(c2, T12, -T11);
        float T14 = __builtin_fmaf(c2, T13, -T12);
        float T15 = __builtin_fmaf(c2, T14, -T13);
        u32x4 lo, hi;
        lo[0] = pk(T0,  T1);  lo[1] = pk(T2,  T3);
        lo[2] = pk(T4,  T5);  lo[3] = pk(T6,  T7);
        hi[0] = pk(T8,  T9);  hi[1] = pk(T10, T11);
        hi[2] = pk(T12, T13); hi[3] = pk(T14, T15);
        if (m == 0) { af00 = lo; af01 = hi; }
        else        { af10 = lo; af11 = hi; }
      }
    }

    const char* bb = bb0 + buf * 16384;
    bf16x8 b00 = *(const bf16x8*)(bb);                 // h=0, n=0
    bf16x8 b01 = *(const bf16x8*)(bb + 256);           // h=0, n=1
    bf16x8 b10 = *(const bf16x8*)(bb + 8192);          // h=1, n=0
    bf16x8 b11 = *(const bf16x8*)(bb + 8192 + 256);    // h=1, n=1
    bf16x8 a00 = *(const bf16x8*)&af00;   // m=0 h=0
    bf16x8 a01 = *(const bf16x8*)&af01;   // m=0 h=1
    bf16x8 a10 = *(const bf16x8*)&af10;   // m=1 h=0
    bf16x8 a11 = *(const bf16x8*)&af11;   // m=1 h=1
    acc[0][0] = __builtin_amdgcn_mfma_f32_16x16x32_bf16(a00, b00, acc[0][0], 0, 0, 0);
    acc[0][1] = __builtin_amdgcn_mfma_f32_16x16x32_bf16(a00, b01, acc[0][1], 0, 0, 0);
    acc[1][0] = __builtin_amdgcn_mfma_f32_16x16x32_bf16(a10, b00, acc[1][0], 0, 0, 0);
    acc[1][1] = __builtin_amdgcn_mfma_f32_16x16x32_bf16(a10, b01, acc[1][1], 0, 0, 0);
    acc[0][0] = __builtin_amdgcn_mfma_f32_16x16x32_bf16(a01, b10, acc[0][0], 0, 0, 0);
    acc[0][1] = __builtin_amdgcn_mfma_f32_16x16x32_bf16(a01, b11, acc[0][1], 0, 0, 0);
    acc[1][0] = __builtin_amdgcn_mfma_f32_16x16x32_bf16(a11, b10, acc[1][0], 0, 0, 0);
    acc[1][1] = __builtin_amdgcn_mfma_f32_16x16x32_bf16(a11, b11, acc[1][1], 0, 0, 0);
  };

  for (int s = 0; s < 136; s += 2) {  // 2-step unroll: buf compile-time
    body(s, 0);
    body(s + 1, 1);
  }

  // epilogue: C/D layout col=l&15, row=(l>>4)*4+r  [m89]
#pragma unroll
  for (int m = 0; m < 2; ++m)
#pragma unroll
    for (int n = 0; n < 2; ++n)
#pragma unroll
      for (int r = 0; r < 4; ++r) {
        int grow = brow + wr * 32 + m * 16 + l4 * 4 + r;
        int gcol = bcol + wc * 32 + n * 16 + l15;
        out[(size_t)grow * OD + gcol] = acc[m][n][r];
      }
}

extern "C" void kernel_launch(void* const* d_in, const int* in_sizes, int n_in,
                              void* d_out, int out_size, void* d_ws, size_t ws_size,
                              hipStream_t stream) {
  const float* x      = (const float*)d_in[0];
  const float* coeffs = (const float*)d_in[1];
  const float* bw     = (const float*)d_in[2];
  float* out = (float*)d_out;
  char* ws = (char*)d_ws;

  float*    t   = (float*)ws;                                  // 16 MB fp32 tanh
  uint16_t* xbf = (uint16_t*)(ws + (size_t)16777216);          // 8 MB bf16 x
  uint16_t* bt2 = (uint16_t*)(ws + (size_t)16777216 + 8388608);// 8.5 MB tiled B

  k_tanh<<<4096, 256, 0, stream>>>(x, t, xbf);
  k_bt<<<1024, 256, 0, stream>>>(coeffs, bw, bt2, out);
  k_gemm<<<512, 512, 0, stream>>>(t, xbf, bt2, out);
}